// Round 7
// baseline (430.452 us; speedup 1.0000x reference)
//
#include <hip/hip_runtime.h>
#include <cstdint>

#define N 8192
#define FIN 256
#define FOUT 128
#define ALPHA 0.2f
#define JP 2                  // j-split (512 gat blocks, 2/CU co-resident)
#define JSL (N / JP)          // 4096 j per block
#define TJ 64                 // j-tile
#define NTILE (JSL / TJ)      // 64 tiles
#define RB 32                 // rows per block
#define SST 72                // S stride in u16 (16B-aligned rows, baseline banks)

typedef unsigned short u16;
typedef unsigned char u8;
typedef __attribute__((ext_vector_type(8))) short short8;
typedef __attribute__((ext_vector_type(4))) float floatx4;

__device__ __forceinline__ u16 bf16_rne(float f) {
  uint32_t u = __float_as_uint(f);
  u += 0x7fff + ((u >> 16) & 1);
  return (u16)(u >> 16);
}

// async global->LDS DMA, 16 B per lane, whole wave. LDS dest = uniform base
// + lane*16 (m104); global src IS per-lane (m173).
__device__ __forceinline__ void gl_lds16(const void* g, void* l) {
  __builtin_amdgcn_global_load_lds(
      (const __attribute__((address_space(1))) void*)g,
      (__attribute__((address_space(3))) void*)l, 16, 0, 0);
}

// ---------------------------------------------------------------------------
// Kernel 1: h = x@W (fp32); hT3 bf16 tiled [jb][nt][m*4+q][8]; src = h@a1,
// dst = h@a2.  (round-2 version, unchanged)
// ---------------------------------------------------------------------------
__global__ __launch_bounds__(256) void k_proj(const float* __restrict__ x,
                                              const float* __restrict__ W,
                                              const float* __restrict__ a,
                                              u16* __restrict__ hT3,
                                              float* __restrict__ srcv,
                                              float* __restrict__ dstv) {
  __shared__ float xs[8 * FIN];                     // 8 KB
  __shared__ float partS[4][4], partD[4][4];
  const int t = threadIdx.x;
  const int R0 = blockIdx.x * 8;

  const float4* xv = (const float4*)(x + (size_t)R0 * FIN);
  float4* xsv = (float4*)xs;
  xsv[t] = xv[t];
  xsv[t + 256] = xv[t + 256];
  __syncthreads();

  const int c  = t & 127;
  const int rg = (t >> 7) * 4;

  float acc[4] = {0.f, 0.f, 0.f, 0.f};
  float wa[4], wb[4];
  #pragma unroll
  for (int j = 0; j < 4; ++j) wa[j] = W[j * FOUT + c];
  #pragma unroll
  for (int j = 0; j < 4; ++j) wb[j] = W[(4 + j) * FOUT + c];

  for (int k4 = 0; k4 < FIN / 4; ++k4) {
    float wc[4];
    #pragma unroll
    for (int j = 0; j < 4; ++j) { wc[j] = wa[j]; wa[j] = wb[j]; }
    const int kn = (k4 + 2 < FIN / 4) ? k4 + 2 : k4;
    #pragma unroll
    for (int j = 0; j < 4; ++j) wb[j] = W[(kn * 4 + j) * FOUT + c];
    #pragma unroll
    for (int i = 0; i < 4; ++i) {
      const float4 xq = *(const float4*)&xs[(rg + i) * FIN + k4 * 4];
      acc[i] += xq.x * wc[0] + xq.y * wc[1] + xq.z * wc[2] + xq.w * wc[3];
    }
  }

  {
    const int j = R0 + rg;
    const int jb = j >> 5, q = (j >> 3) & 3, jj = j & 7;
    const int m = c & 15, nt = c >> 4;
    union { u16 u[4]; uint2 v; } pk;
    #pragma unroll
    for (int i = 0; i < 4; ++i) pk.u[i] = bf16_rne(acc[i]);
    *(uint2*)(hT3 + (size_t)(((jb * 8 + nt) * 64) + (m * 4 + q)) * 8 + jj) = pk.v;
  }

  const float a1 = a[c], a2 = a[FOUT + c];
  float s4[4], d4[4];
  #pragma unroll
  for (int i = 0; i < 4; ++i) { s4[i] = acc[i] * a1; d4[i] = acc[i] * a2; }
  #pragma unroll
  for (int off = 32; off > 0; off >>= 1) {
    #pragma unroll
    for (int i = 0; i < 4; ++i) {
      s4[i] += __shfl_down(s4[i], off);
      d4[i] += __shfl_down(d4[i], off);
    }
  }
  const int wv = t >> 6, lane = t & 63;
  if (lane == 0) {
    #pragma unroll
    for (int i = 0; i < 4; ++i) { partS[wv][i] = s4[i]; partD[wv][i] = d4[i]; }
  }
  __syncthreads();
  if (t < 16) {
    const int i = t & 3, rg2 = (t >> 2) & 1, which = t >> 3;
    if (which == 0) srcv[R0 + rg2 * 4 + i] = partS[rg2*2][i] + partS[rg2*2+1][i];
    else            dstv[R0 + rg2 * 4 + i] = partD[rg2*2][i] + partD[rg2*2+1][i];
  }
}

// ---------------------------------------------------------------------------
// Kernel 2: fused GAT — round-7: TRIPLE-buffered DMA pipeline.
// r6 diagnosis: B1's vmcnt(2) drained all 6 DMAs every iter -> avg
// outstanding ~6-8 KB/CU -> Little's law caps adj at ~5 B/cyc/CU (measured
// 3.3 TB/s, half the per-CU HBM share) -> adj cost additive (+0.33 us/iter).
// Fix: 3 buffers, STAGE(i+2) issued each iter, retired TWO iters later:
//   queue entering B1(i) = [S(i):6, dst(i):2, S(i+1):6] = 14
//   B1 = vmcnt(8): retires exactly S(i); >=8 ops (~14 KB/blk) always in
//   flight -> full 10 B/cyc/CU share. Issue order dst(i+1) BEFORE
//   STAGE(i+2): p-phase's implicit wait for dst(i) (2 oldest) is vmcnt(14)
//   — never touches a DMA. Last iter peeled with vmcnt(2) (no younger
//   STAGE -> vmcnt(8) would be vacuous and race S(NTILE-1)).
// LDS 76.5 KB -> 2 blocks/CU (grid 512 = 2/CU exact).
// ---------------------------------------------------------------------------
__global__ __launch_bounds__(256, 2) void k_gat(const int* __restrict__ adj,
                                                const u16* __restrict__ hT3,
                                                const float* __restrict__ srcv,
                                                const float* __restrict__ dstv,
                                                float* __restrict__ P,
                                                float* __restrict__ lp) {
  __shared__ u16 hS[3][8192];      // 3 x 16 KB staged hT tiles
  __shared__ int adjS[3][2048];    // 3 x 8 KB staged adj tiles (32 x 64 int)
  __shared__ u16 S[RB * SST];      // 4.6 KB p-tile (bf16)
  const int t = threadIdx.x;
  const int wv = t >> 6, lane = t & 63;
  const int q = lane >> 4, m = lane & 15;
  const int bm = blockIdx.x & 255;
  const int jp = blockIdx.x >> 8;
  const int R0 = bm * RB;
  const int j0 = jp * JSL;

  // p-phase mapping: thread -> (row pr, 8 cols at pc)
  const int pr = t >> 3;
  const int pc = (t & 7) * 8;
  const float srcr = srcv[R0 + pr];
  const float* dstp = dstv + j0 + pc;

  // MFMA mapping: wave -> (row-half rh, col-half ch)
  const int rh = wv & 1, ch = wv >> 1;
  const int Lq = m * 4 + q;                      // hT3/hS lane index

  floatx4 acc[4];
  #pragma unroll
  for (int nt = 0; nt < 4; ++nt) acc[nt] = (floatx4){0.f, 0.f, 0.f, 0.f};
  float lsum = 0.f;

  // rotating buffer pointers (h0/a0 = current tile i; h2/a2 = DMA target i+2)
  u16* h0 = &hS[0][0]; u16* h1 = &hS[1][0]; u16* h2 = &hS[2][0];
  int* a0 = &adjS[0][0]; int* a1 = &adjS[1][0]; int* a2 = &adjS[2][0];

  // DMA one tile: hT 16 KB (16 chunks, wave wv: 4) + adj 8 KB (8 chunks,
  // wave wv: 2). adj chunk c_ (1 KB): rows c_*4+(lane>>4), cols (lane&15)*4
  // -> LDS row-major [32][64] int (lane-linear ✓).
  const size_t jb00 = (size_t)(j0 >> 5);         // first global jb of slice
  #define STAGE(I, HD, AD)                                                     \
  {                                                                            \
    _Pragma("unroll")                                                          \
    for (int cc = 0; cc < 4; ++cc) {                                           \
      const int kc = wv * 4 + cc;               /* 0..15 */                    \
      const int jbl = kc >> 3, nt_ = kc & 7;                                   \
      const u16* src = hT3 + ((jb00 + (size_t)(I) * 2 + jbl) * 8 + nt_) * 512  \
                       + (size_t)lane * 8;                                     \
      gl_lds16(src, (HD) + kc * 512);                                          \
    }                                                                          \
    _Pragma("unroll")                                                          \
    for (int cc = 0; cc < 2; ++cc) {                                           \
      const int c_ = wv * 2 + cc;               /* 0..7 */                     \
      const int* asrc = adj + (size_t)(R0 + c_ * 4 + (lane >> 4)) * N          \
                        + j0 + (I) * TJ + (lane & 15) * 4;                     \
      gl_lds16(asrc, (AD) + c_ * 256);                                         \
    }                                                                          \
  }

  // p-phase + store to S (consumes dC regs + A regs)
  #define PPHASE(A0_, A1_, dC0_, dC1_)                                         \
  {                                                                            \
    const int   ai[8] = {A0_.x, A0_.y, A0_.z, A0_.w, A1_.x, A1_.y, A1_.z, A1_.w}; \
    const float df[8] = {dC0_.x, dC0_.y, dC0_.z, dC0_.w, dC1_.x, dC1_.y, dC1_.z, dC1_.w}; \
    union { u16 u[8]; short8 s; } pk;                                          \
    _Pragma("unroll")                                                          \
    for (int e = 0; e < 8; ++e) {                                              \
      float v = srcr + df[e];                                                  \
      v = fmaxf(v, ALPHA * v);                                                 \
      const float p = ai[e] > 0 ? __expf(v) : 0.f;                             \
      lsum += p;                                                               \
      pk.u[e] = bf16_rne(p);                                                   \
    }                                                                          \
    *(short8*)&S[pr * SST + pc] = pk.s;                                        \
  }

  // MFMA phase reading S + current hT buffer
  #define MFMAPH(HB)                                                           \
  {                                                                            \
    const short8 a0f = *(const short8*)&S[(rh * 16 + m) * SST + q * 8];        \
    const short8 a1f = *(const short8*)&S[(rh * 16 + m) * SST + 32 + q * 8];   \
    _Pragma("unroll")                                                          \
    for (int nt = 0; nt < 4; ++nt) {                                           \
      const short8 b0 = *(const short8*)&(HB)[(0 * 8 + ch * 4 + nt) * 512 + Lq * 8]; \
      const short8 b1 = *(const short8*)&(HB)[(1 * 8 + ch * 4 + nt) * 512 + Lq * 8]; \
      acc[nt] = __builtin_amdgcn_mfma_f32_16x16x32_bf16(a0f, b0, acc[nt], 0, 0, 0); \
      acc[nt] = __builtin_amdgcn_mfma_f32_16x16x32_bf16(a1f, b1, acc[nt], 0, 0, 0); \
    }                                                                          \
  }

  // prologue: S(0), dst(0), S(1)  -> queue [S(0):6, dst(0):2, S(1):6] = 14
  STAGE(0, h0, a0)
  __builtin_amdgcn_sched_barrier(0);
  float4 dC0 = *(const float4*)(dstp),   dC1 = *(const float4*)(dstp + 4);
  __builtin_amdgcn_sched_barrier(0);
  STAGE(1, h1, a1)
  __builtin_amdgcn_sched_barrier(0);

  for (int i = 0; i < NTILE - 1; ++i) {
    // B1: vmcnt(8) retires exactly S(i) (oldest 6 of 14); keeps
    // [dst(i):2, S(i+1):6] in flight. lgkmcnt(0): all waves' prior LDS
    // reads done before S / h2 / a2 get overwritten after the barrier.
    asm volatile("s_waitcnt vmcnt(8) lgkmcnt(0)" ::: "memory");
    __builtin_amdgcn_s_barrier();
    __builtin_amdgcn_sched_barrier(0);

    // mask for tile i from a0 (retired at B1)
    const int4 A0 = *((const int4*)a0 + pr * 16 + (t & 7) * 2);
    const int4 A1 = *((const int4*)a0 + pr * 16 + (t & 7) * 2 + 1);
    __builtin_amdgcn_sched_barrier(0);

    // dst(i+1) FIRST (so p-phase's dst(i) wait never touches a DMA) ...
    float4 dN0 = *(const float4*)(dstp + (i + 1) * TJ);
    float4 dN1 = *(const float4*)(dstp + (i + 1) * TJ + 4);
    __builtin_amdgcn_sched_barrier(0);
    // ... then STAGE(i+2) into the third buffer (retired at B1(i+2))
    if (i + 2 < NTILE) STAGE(i + 2, h2, a2)
    __builtin_amdgcn_sched_barrier(0);

    // p-phase: consumes dC=dst(i) (implicit vmcnt retires only dst(i))
    PPHASE(A0, A1, dC0, dC1)

    // B2: LDS-only barrier — S visible; DMAs stay in flight (no vmcnt)
    asm volatile("s_waitcnt lgkmcnt(0)" ::: "memory");
    __builtin_amdgcn_s_barrier();
    __builtin_amdgcn_sched_barrier(0);

    MFMAPH(h0)

    // rotate buffers: current <- i+1, DMA target <- freed
    u16* ht = h0; h0 = h1; h1 = h2; h2 = ht;
    int* at = a0; a0 = a1; a1 = a2; a2 = at;
    dC0 = dN0; dC1 = dN1;
  }

  // peeled last iteration: no younger STAGE exists -> vmcnt(8) would be
  // vacuous; vmcnt(2) retires S(NTILE-1), keeps the 2 stale dst loads.
  asm volatile("s_waitcnt vmcnt(2) lgkmcnt(0)" ::: "memory");
  __builtin_amdgcn_s_barrier();
  __builtin_amdgcn_sched_barrier(0);
  {
    const int4 A0 = *((const int4*)a0 + pr * 16 + (t & 7) * 2);
    const int4 A1 = *((const int4*)a0 + pr * 16 + (t & 7) * 2 + 1);
    PPHASE(A0, A1, dC0, dC1)
  }
  asm volatile("s_waitcnt lgkmcnt(0)" ::: "memory");
  __builtin_amdgcn_s_barrier();
  __builtin_amdgcn_sched_barrier(0);
  MFMAPH(h0)
  #undef STAGE
  #undef PPHASE
  #undef MFMAPH

  // row-sum: reduce over the 8 threads sharing row pr (aligned groups)
  lsum += __shfl_down(lsum, 4);
  lsum += __shfl_down(lsum, 2);
  lsum += __shfl_down(lsum, 1);
  if ((t & 7) == 0) lp[(size_t)jp * N + R0 + pr] = lsum;

  // partial store (C/D layout: row = q*4+ri, col = nt*16+m)
  float* Pp = P + ((size_t)jp * N + R0 + rh * 16) * FOUT + ch * 64;
  #pragma unroll
  for (int nt = 0; nt < 4; ++nt)
    #pragma unroll
    for (int ri = 0; ri < 4; ++ri)
      Pp[(size_t)(q * 4 + ri) * FOUT + nt * 16 + m] = acc[nt][ri];
}

// ---------------------------------------------------------------------------
// Kernel 3: sum JP partials, normalize by row-sum. ~20 MB traffic at JP=2.
// ---------------------------------------------------------------------------
__global__ __launch_bounds__(256) void k_norm(const float* __restrict__ P,
                                              const float* __restrict__ lp,
                                              float* __restrict__ out) {
  const int idx = blockIdx.x * 256 + threadIdx.x;   // 0 .. N*FOUT/4-1
  const int rr = idx >> 5;
  const int c4 = (idx & 31) * 4;
  float l = 0.f;
  #pragma unroll
  for (int j = 0; j < JP; ++j) l += lp[j * N + rr];
  const float inv = 1.0f / l;
  float4 s = {0.f, 0.f, 0.f, 0.f};
  #pragma unroll
  for (int j = 0; j < JP; ++j) {
    const float4 p = *(const float4*)(P + ((size_t)j * N + rr) * FOUT + c4);
    s.x += p.x; s.y += p.y; s.z += p.z; s.w += p.w;
  }
  s.x *= inv; s.y *= inv; s.z *= inv; s.w *= inv;
  *(float4*)(out + (size_t)rr * FOUT + c4) = s;
}

extern "C" void kernel_launch(void* const* d_in, const int* in_sizes, int n_in,
                              void* d_out, int out_size, void* d_ws, size_t ws_size,
                              hipStream_t stream) {
  const float* x   = (const float*)d_in[0];
  const int*   adj = (const int*)d_in[1];
  const float* W   = (const float*)d_in[2];
  const float* a   = (const float*)d_in[3];
  float* out = (float*)d_out;

  char* ws = (char*)d_ws;
  u16*   hT3  = (u16*)ws;     ws += (size_t)FOUT * N * sizeof(u16);            // 2 MB
  float* srcv = (float*)ws;   ws += (size_t)N * sizeof(float);
  float* dstv = (float*)ws;   ws += (size_t)N * sizeof(float);
  float* P    = (float*)ws;   ws += (size_t)JP * N * FOUT * sizeof(float);     // 8 MB
  float* lp   = (float*)ws;   ws += (size_t)JP * N * sizeof(float);

  k_proj<<<N / 8, 256, 0, stream>>>(x, W, a, hT3, srcv, dstv);
  k_gat <<<256 * JP, 256, 0, stream>>>(adj, hT3, srcv, dstv, P, lp);
  k_norm<<<(N * FOUT / 4) / 256, 256, 0, stream>>>(P, lp, out);
}